// Round 1
// baseline (89.263 us; speedup 1.0000x reference)
//
#include <hip/hip_runtime.h>
#include <math.h>

#define IN_LEN 8
#define OUT_LEN 8
#define N_OUT_CAPS 8
#define FI 8
#define HIN 32
#define WIN 32
#define CIN 64
#define HO 64
#define WO 64
#define NITER 3

// Weight LDS layout: [tap(h*3+w)][m][g][l] -> ((tap*8 + m)*8 + g)*8 + l
// - per-thread dot over l: 8 contiguous floats -> 2x ds_read_b128
// - across lanes (g varies, s broadcast): 8 distinct 32B-strided addrs, light conflicts
__global__ __launch_bounds__(256) void caps_routing_kernel(
    const float* __restrict__ in,      // (2,64,32,32)
    const float* __restrict__ weight,  // (8,8,8,3,3) = [l][g][m][kh][kw]
    const float* __restrict__ bias,    // (8,8)
    float* __restrict__ out)           // (2,64,64,64)
{
    __shared__ float wlds[9 * OUT_LEN * N_OUT_CAPS * IN_LEN]; // 4608 floats = 18 KB

    const int tid = threadIdx.x;

    // Stage flipped weight into LDS: wflip[l,g,m,h,w] = weight[l,g,m,2-h,2-w]
    for (int i = tid; i < 4608; i += 256) {
        int w_ = i % 3;
        int h_ = (i / 3) % 3;
        int m_ = (i / 9) % 8;
        int g_ = (i / 72) % 8;
        int l_ = i / 576;
        int tap = (2 - h_) * 3 + (2 - w_);
        wlds[((tap * 8 + m_) * 8 + g_) * 8 + l_] = weight[i];
    }
    __syncthreads();

    const int wave = tid >> 6;
    const int lane = tid & 63;
    const int g = lane >> 3;   // output capsule
    const int s = lane & 7;    // input-capsule group f owned by this thread

    const int pos = blockIdx.x * 4 + wave;  // 0..8191 = n*4096 + p*64 + q
    const int n = pos >> 12;
    const int p = (pos >> 6) & 63;
    const int q = pos & 63;

    // ---- compute priors: 9 taps x 8 dims, zero for invalid taps ----
    float pri[9][8];
#pragma unroll
    for (int j = 0; j < 9; ++j)
#pragma unroll
        for (int m = 0; m < 8; ++m) pri[j][m] = 0.f;

    const float* inbase = in + (size_t)(n * CIN + s * IN_LEN) * HIN * WIN;

#pragma unroll
    for (int h = 0; h < 3; ++h) {
        const int yy = p + h - 1;
        const bool vh = (yy >= 0) && ((yy & 1) == 0) && ((yy >> 1) < HIN);
        const int y = yy >> 1;
#pragma unroll
        for (int w = 0; w < 3; ++w) {
            const int xx = q + w - 1;
            const bool vw = (xx >= 0) && ((xx & 1) == 0) && ((xx >> 1) < WIN);
            const int x = xx >> 1;
            if (vh && vw) {   // wave-uniform branch (p,q uniform per wave)
                float xv[8];
#pragma unroll
                for (int l = 0; l < 8; ++l)
                    xv[l] = inbase[(l * HIN + y) * WIN + x];
                const int tap = h * 3 + w;
#pragma unroll
                for (int m = 0; m < 8; ++m) {
                    const float4* wp =
                        (const float4*)&wlds[((tap * 8 + m) * 8 + g) * 8];
                    float4 w0 = wp[0];
                    float4 w1 = wp[1];
                    pri[tap][m] = xv[0] * w0.x + xv[1] * w0.y + xv[2] * w0.z +
                                  xv[3] * w0.w + xv[4] * w1.x + xv[5] * w1.y +
                                  xv[6] * w1.z + xv[7] * w1.w;
                }
            }
        }
    }

    // 8-lane butterfly reductions (groups aligned to 8 lanes)
    auto red8 = [](float v) {
        v += __shfl_xor(v, 1, 64);
        v += __shfl_xor(v, 2, 64);
        v += __shfl_xor(v, 4, 64);
        return v;
    };
    auto redmax8 = [](float v) {
        v = fmaxf(v, __shfl_xor(v, 1, 64));
        v = fmaxf(v, __shfl_xor(v, 2, 64));
        v = fmaxf(v, __shfl_xor(v, 4, 64));
        return v;
    };

    // ---- init: out = mean over 72 votes ----
    float o[8];
#pragma unroll
    for (int m = 0; m < 8; ++m) {
        float a = 0.f;
#pragma unroll
        for (int j = 0; j < 9; ++j) a += pri[j][m];
        o[m] = red8(a) * (1.f / 72.f);
    }

    // ---- 3 routing iterations ----
#pragma unroll
    for (int it = 0; it < NITER; ++it) {
        float sn = 0.f;
#pragma unroll
        for (int m = 0; m < 8; ++m) sn += o[m] * o[m];
        const float inv = 1.f / fmaxf(sqrtf(sn), 1e-12f);
        float on[8];
#pragma unroll
        for (int m = 0; m < 8; ++m) on[m] = o[m] * inv;

        float lg[9];
#pragma unroll
        for (int j = 0; j < 9; ++j) {
            float a = 0.f;
#pragma unroll
            for (int m = 0; m < 8; ++m) a += pri[j][m] * on[m];
            lg[j] = a;
        }
        float mx = lg[0];
#pragma unroll
        for (int j = 1; j < 9; ++j) mx = fmaxf(mx, lg[j]);
        mx = redmax8(mx);

        float e[9];
        float ssum = 0.f;
#pragma unroll
        for (int j = 0; j < 9; ++j) {
            e[j] = __expf(lg[j] - mx);
            ssum += e[j];
        }
        ssum = red8(ssum);
        const float invs = 1.f / ssum;

#pragma unroll
        for (int m = 0; m < 8; ++m) {
            float a = 0.f;
#pragma unroll
            for (int j = 0; j < 9; ++j) a += e[j] * pri[j][m];
            o[m] = red8(a) * invs;
        }
    }

    // ---- squash + bias + store ----
    float sn = 0.f;
#pragma unroll
    for (int m = 0; m < 8; ++m) sn += o[m] * o[m];
    const float factor = sn / ((1.f + sn) * sqrtf(sn + 1e-12f));

    // lane s writes output dim m = s
    float val = o[0];
#pragma unroll
    for (int m = 1; m < 8; ++m)
        if (s == m) val = o[m];
    val = val * factor + bias[g * 8 + s];

    out[(((size_t)n * 64 + g * 8 + s) * 64 + p) * 64 + q] = val;
}

extern "C" void kernel_launch(void* const* d_in, const int* in_sizes, int n_in,
                              void* d_out, int out_size, void* d_ws, size_t ws_size,
                              hipStream_t stream) {
    const float* in = (const float*)d_in[0];
    const float* weight = (const float*)d_in[1];
    const float* bias = (const float*)d_in[2];
    float* out = (float*)d_out;
    // 8192 (n,p,q) positions, 4 per block (1 wave each)
    caps_routing_kernel<<<2048, 256, 0, stream>>>(in, weight, bias, out);
}